// Round 1
// baseline (888.076 us; speedup 1.0000x reference)
//
#include <hip/hip_runtime.h>
#include <hip/hip_bf16.h>
#include <stdint.h>

#define SEQ 3072
#define NH  16
#define DH  64
#define QT  64          // q rows per block
#define KT  64          // key tile
#define NKT (SEQ / KT)  // 48
#define NWORDS (SEQ * SEQ / 64)

// ---------------- mask dtype detection ----------------
// flag: 1 = int32 (0/1), 2 = float32 (0.0/1.0), 0 = byte (bool)
__global__ void detect_kernel(const uint32_t* __restrict__ m, int* __restrict__ flag) {
    __shared__ int cntA, cntB;
    if (threadIdx.x == 0) { cntA = 0; cntB = 0; }
    __syncthreads();
    int a = 0, b = 0;
    for (int i = 0; i < 16; ++i) {
        uint32_t w = m[threadIdx.x + i * 256];
        if (w & 0xFFFFFF00u) a = 1;   // nonzero high bytes -> not int32 0/1
        if (w & 0x0000FFFFu) b = 1;   // nonzero low half  -> not float 0/1.0
    }
    if (a) atomicOr(&cntA, 1);
    if (b) atomicOr(&cntB, 1);
    __syncthreads();
    if (threadIdx.x == 0)
        *flag = (cntA == 0) ? 1 : ((cntB == 0) ? 2 : 0);
}

// ---------------- mask -> bitmask pack ----------------
__global__ void pack_kernel(const void* __restrict__ mask, const int* __restrict__ flag,
                            uint64_t* __restrict__ bits) {
    int g = blockIdx.x * 256 + threadIdx.x;
    int f = *flag;
    bool v;
    if (f == 1)      v = ((const int*)mask)[g] != 0;
    else if (f == 2) v = ((const float*)mask)[g] != 0.0f;
    else             v = ((const unsigned char*)mask)[g] != 0;
    uint64_t b = __ballot(v);
    if ((threadIdx.x & 63) == 0) bits[g >> 6] = b;
}

// ---------------- flash attention (fp32 vector) ----------------
// grid (NKT_q=48, H=16), block 256 = 4 waves.
// wave handles 16 q-rows; 4 lanes per row, each lane owns 16 dims.
template <bool USE_BITS>
__global__ __launch_bounds__(256, 2)
void attn_kernel(const float* __restrict__ Q, const float* __restrict__ K,
                 const float* __restrict__ V,
                 const uint64_t* __restrict__ maskbits,
                 const int* __restrict__ mask_i32,
                 float* __restrict__ out) {
    const int qtile = blockIdx.x;
    const int h     = blockIdx.y;
    const int tid   = threadIdx.x;
    const int wave  = tid >> 6;
    const int lane  = tid & 63;
    const int r     = lane >> 2;       // row within wave: 0..15
    const int p     = lane & 3;        // dim quarter: 0..3
    const int qrow  = qtile * QT + wave * 16 + r;

    __shared__ float Kt[KT][DH + 4];
    __shared__ float Vt[KT][DH + 4];

    const float scale = 0.125f;  // 1/sqrt(64)
    float q[16];
    const float* qptr = Q + (qrow * NH + h) * DH + p * 16;
    #pragma unroll
    for (int j = 0; j < 16; j += 4) {
        float4 t = *(const float4*)(qptr + j);
        q[j+0] = t.x * scale; q[j+1] = t.y * scale;
        q[j+2] = t.z * scale; q[j+3] = t.w * scale;
    }

    float acc[16];
    #pragma unroll
    for (int j = 0; j < 16; ++j) acc[j] = 0.0f;
    float m = -1e30f, l = 0.0f;

    const int srow   = tid >> 2;        // staging row 0..63
    const int schunk = (tid & 3) * 16;  // staging col base

    for (int kt = 0; kt < NKT; ++kt) {
        __syncthreads();
        {
            const int krow  = kt * KT + srow;
            const float* kp = K + (krow * NH + h) * DH + schunk;
            const float* vp = V + (krow * NH + h) * DH + schunk;
            #pragma unroll
            for (int c = 0; c < 16; c += 4) {
                *(float4*)&Kt[srow][schunk + c] = *(const float4*)(kp + c);
                *(float4*)&Vt[srow][schunk + c] = *(const float4*)(vp + c);
            }
        }
        __syncthreads();

        uint64_t mw;
        if (USE_BITS) {
            mw = maskbits[qrow * NKT + kt];
        }

        for (int k = 0; k < KT; ++k) {
            float s = 0.0f;
            #pragma unroll
            for (int j = 0; j < 16; ++j)
                s = fmaf(q[j], Kt[k][p * 16 + j], s);
            s += __shfl_xor(s, 1);
            s += __shfl_xor(s, 2);

            bool keep;
            if (USE_BITS) keep = (mw >> k) & 1;
            else          keep = mask_i32[qrow * SEQ + kt * KT + k] != 0;

            float seff = keep ? s : -1e30f;
            if (seff > m) {               // rare (~ln(S) per row): branch ok
                float alpha = __expf(m - seff);
                l *= alpha;
                #pragma unroll
                for (int j = 0; j < 16; ++j) acc[j] *= alpha;
                m = seff;
            }
            float pv = keep ? __expf(s - m) : 0.0f;
            l += pv;
            #pragma unroll
            for (int j = 0; j < 16; ++j)
                acc[j] = fmaf(pv, Vt[k][p * 16 + j], acc[j]);
        }
    }

    float inv = (l > 0.0f) ? (1.0f / l) : 0.0f;
    float* op = out + (qrow * NH + h) * DH + p * 16;
    #pragma unroll
    for (int j = 0; j < 16; j += 4) {
        float4 t;
        t.x = acc[j+0] * inv; t.y = acc[j+1] * inv;
        t.z = acc[j+2] * inv; t.w = acc[j+3] * inv;
        *(float4*)(op + j) = t;
    }
}

extern "C" void kernel_launch(void* const* d_in, const int* in_sizes, int n_in,
                              void* d_out, int out_size, void* d_ws, size_t ws_size,
                              hipStream_t stream) {
    const float* Q    = (const float*)d_in[0];
    const float* K    = (const float*)d_in[1];
    const float* V    = (const float*)d_in[2];
    const void*  mask = d_in[3];
    float* out = (float*)d_out;

    const size_t need = 64 + (size_t)NWORDS * 8;
    if (ws_size >= need) {
        int*      flag = (int*)d_ws;
        uint64_t* bits = (uint64_t*)((char*)d_ws + 64);
        detect_kernel<<<1, 256, 0, stream>>>((const uint32_t*)mask, flag);
        pack_kernel<<<SEQ * SEQ / 256, 256, 0, stream>>>(mask, flag, bits);
        attn_kernel<true><<<dim3(NKT, NH), 256, 0, stream>>>(Q, K, V, bits, nullptr, out);
    } else {
        // fallback: assume int32 mask, read directly (L2/LLC-cached)
        attn_kernel<false><<<dim3(NKT, NH), 256, 0, stream>>>(Q, K, V, nullptr,
                                                              (const int*)mask, out);
    }
}

// Round 2
// 184.716 us; speedup vs baseline: 4.8078x; 4.8078x over previous
//
#include <hip/hip_runtime.h>
#include <stdint.h>

#define SEQ 3072
#define NH  16
#define DH  64
#define QBLK 64
#define KVBLK 64
#define NKT (SEQ / KVBLK)   // 48
#define NQT (SEQ / QBLK)    // 48
#define NWORDS (SEQ * SEQ / 64)

typedef __attribute__((ext_vector_type(8))) __bf16 bf16x8;
typedef __attribute__((ext_vector_type(4))) float f32x4;

union BF8 { ushort us[8]; uint4 u4; bf16x8 v; };

__device__ __forceinline__ ushort f2bf(float f) {
    uint u = __builtin_bit_cast(uint, f);
    return (ushort)((u + 0x7FFFu + ((u >> 16) & 1u)) >> 16);
}

// ---------------- mask dtype detection ----------------
__global__ void detect_kernel(const uint32_t* __restrict__ m, int* __restrict__ flag) {
    __shared__ int cntA, cntB;
    if (threadIdx.x == 0) { cntA = 0; cntB = 0; }
    __syncthreads();
    int a = 0, b = 0;
    for (int i = 0; i < 16; ++i) {
        uint32_t w = m[threadIdx.x + i * 256];
        if (w & 0xFFFFFF00u) a = 1;
        if (w & 0x0000FFFFu) b = 1;
    }
    if (a) atomicOr(&cntA, 1);
    if (b) atomicOr(&cntB, 1);
    __syncthreads();
    if (threadIdx.x == 0) *flag = (cntA == 0) ? 1 : ((cntB == 0) ? 2 : 0);
}

// ---------------- mask -> bitmask pack ----------------
__global__ void pack_kernel(const void* __restrict__ mask, const int* __restrict__ flag,
                            uint64_t* __restrict__ bits) {
    int g = blockIdx.x * 256 + threadIdx.x;
    int f = *flag;
    bool v;
    if (f == 1)      v = ((const int*)mask)[g] != 0;
    else if (f == 2) v = ((const float*)mask)[g] != 0.0f;
    else             v = ((const unsigned char*)mask)[g] != 0;
    uint64_t b = __ballot(v);
    if ((threadIdx.x & 63) == 0) bits[g >> 6] = b;
}

// ---------------- MFMA flash attention ----------------
// grid (NQT, NH), 256 threads = 4 waves, wave owns 16 q-rows.
// mfma_f32_16x16x32_bf16: A lane: row=l&15, k=8*(l>>4)+j ; D lane: col=l&15, row=4*(l>>4)+r.
template <bool USE_BITS>
__global__ __launch_bounds__(256, 2)
void attn_mfma(const float* __restrict__ Q, const float* __restrict__ K,
               const float* __restrict__ V, const uint64_t* __restrict__ bits,
               const int* __restrict__ mask_i32, float* __restrict__ out)
{
    const int qtile = blockIdx.x, h = blockIdx.y;
    const int tid  = threadIdx.x;
    const int wv   = tid >> 6, lane = tid & 63;
    const int g    = lane >> 4, c = lane & 15;
    const int qb   = qtile * QBLK + wv * 16;

    // K: rows=key, cols=d (chunk-swizzled ^ (row&7)); Vt: rows=d, cols=key (^ ((d>>3)&7))
    __shared__ __align__(16) ushort KbS[KVBLK * 72];
    __shared__ __align__(16) ushort VtS[DH * 72];
    __shared__ __align__(16) ushort PbS[4 * 16 * 72];
    ushort* Pw = &PbS[wv * 16 * 72];

    // Q fragments, scale folded in
    bf16x8 qa[2];
    {
        const float* qp = Q + ((qb + c) * NH + h) * DH;
        #pragma unroll
        for (int kk = 0; kk < 2; ++kk) {
            BF8 t;
            const float4* p = (const float4*)(qp + kk * 32 + g * 8);
            float4 f0 = p[0], f1 = p[1];
            t.us[0] = f2bf(f0.x * 0.125f); t.us[1] = f2bf(f0.y * 0.125f);
            t.us[2] = f2bf(f0.z * 0.125f); t.us[3] = f2bf(f0.w * 0.125f);
            t.us[4] = f2bf(f1.x * 0.125f); t.us[5] = f2bf(f1.y * 0.125f);
            t.us[6] = f2bf(f1.z * 0.125f); t.us[7] = f2bf(f1.w * 0.125f);
            qa[kk] = t.v;
        }
    }

    f32x4 oacc[4];
    float m_[4], lsum[4];
    #pragma unroll
    for (int nt = 0; nt < 4; ++nt) oacc[nt] = (f32x4){0.f, 0.f, 0.f, 0.f};
    #pragma unroll
    for (int r = 0; r < 4; ++r) { m_[r] = -1e30f; lsum[r] = 0.f; }

    const int srow0 = tid >> 3;   // 0..31
    const int fch   = tid & 7;    // 8-float chunk

    for (int kt = 0; kt < NKT; ++kt) {
        __syncthreads();
        // ---- stage K (row-major bf16, swizzled) and V (transposed, swizzled) ----
        #pragma unroll
        for (int i = 0; i < 2; ++i) {
            const int krow = srow0 + 32 * i;
            const int gofs = ((kt * KVBLK + krow) * NH + h) * DH + fch * 8;
            const float4* kp = (const float4*)(K + gofs);
            const float4* vp = (const float4*)(V + gofs);
            float4 k0 = kp[0], k1 = kp[1];
            float4 v0 = vp[0], v1 = vp[1];
            BF8 kb;
            kb.us[0] = f2bf(k0.x); kb.us[1] = f2bf(k0.y);
            kb.us[2] = f2bf(k0.z); kb.us[3] = f2bf(k0.w);
            kb.us[4] = f2bf(k1.x); kb.us[5] = f2bf(k1.y);
            kb.us[6] = f2bf(k1.z); kb.us[7] = f2bf(k1.w);
            *(uint4*)&KbS[krow * 72 + (fch ^ (krow & 7)) * 8] = kb.u4;
            float vf[8] = {v0.x, v0.y, v0.z, v0.w, v1.x, v1.y, v1.z, v1.w};
            #pragma unroll
            for (int j = 0; j < 8; ++j) {
                const int d = fch * 8 + j;
                VtS[d * 72 + ((krow >> 3) ^ ((d >> 3) & 7)) * 8 + (krow & 7)] = f2bf(vf[j]);
            }
        }
        __syncthreads();

        // ---- mask words (one u64 per q-row per kv-tile) ----
        uint64_t mw[4];
        if (USE_BITS) {
            #pragma unroll
            for (int r = 0; r < 4; ++r)
                mw[r] = bits[(qb + 4 * g + r) * NKT + kt];
        }

        // ---- QK^T ----
        f32x4 sacc[4];
        #pragma unroll
        for (int nt = 0; nt < 4; ++nt) sacc[nt] = (f32x4){0.f, 0.f, 0.f, 0.f};
        #pragma unroll
        for (int kk = 0; kk < 2; ++kk) {
            #pragma unroll
            for (int nt = 0; nt < 4; ++nt) {
                const int krow = nt * 16 + c;
                bf16x8 kf = *(const bf16x8*)&KbS[krow * 72 + (((g + 4 * kk) ^ (krow & 7))) * 8];
                sacc[nt] = __builtin_amdgcn_mfma_f32_16x16x32_bf16(qa[kk], kf, sacc[nt], 0, 0, 0);
            }
        }

        // ---- mask apply + row max ----
        float pmax[4];
        #pragma unroll
        for (int r = 0; r < 4; ++r) pmax[r] = -1e30f;
        #pragma unroll
        for (int nt = 0; nt < 4; ++nt) {
            #pragma unroll
            for (int r = 0; r < 4; ++r) {
                bool keep;
                if (USE_BITS) keep = (mw[r] >> (nt * 16 + c)) & 1ull;
                else keep = mask_i32[(size_t)(qb + 4 * g + r) * SEQ + kt * KVBLK + nt * 16 + c] != 0;
                float s = keep ? sacc[nt][r] : -1e30f;
                sacc[nt][r] = s;
                pmax[r] = fmaxf(pmax[r], s);
            }
        }
        // ---- online rescale ----
        #pragma unroll
        for (int r = 0; r < 4; ++r) {
            float v = pmax[r];
            v = fmaxf(v, __shfl_xor(v, 1));
            v = fmaxf(v, __shfl_xor(v, 2));
            v = fmaxf(v, __shfl_xor(v, 4));
            v = fmaxf(v, __shfl_xor(v, 8));
            float nm = fmaxf(m_[r], v);
            float alpha = __expf(m_[r] - nm);
            m_[r] = nm;
            lsum[r] *= alpha;
            #pragma unroll
            for (int nt = 0; nt < 4; ++nt) oacc[nt][r] *= alpha;
        }
        // ---- P = exp(s-m), write to per-wave LDS (D-layout -> A-layout transpose) ----
        #pragma unroll
        for (int nt = 0; nt < 4; ++nt) {
            #pragma unroll
            for (int r = 0; r < 4; ++r) {
                float p = __expf(sacc[nt][r] - m_[r]);
                lsum[r] += p;
                const int row = 4 * g + r, col = nt * 16 + c;
                Pw[row * 72 + (((col >> 3) ^ (row & 7))) * 8 + (col & 7)] = f2bf(p);
            }
        }
        // ---- PV ----
        #pragma unroll
        for (int kk = 0; kk < 2; ++kk) {
            bf16x8 pa = *(const bf16x8*)&Pw[c * 72 + (((g + 4 * kk) ^ (c & 7))) * 8];
            #pragma unroll
            for (int nt = 0; nt < 4; ++nt) {
                const int d = nt * 16 + c;
                bf16x8 vb = *(const bf16x8*)&VtS[d * 72 + (((g + 4 * kk) ^ ((d >> 3) & 7))) * 8];
                oacc[nt] = __builtin_amdgcn_mfma_f32_16x16x32_bf16(pa, vb, oacc[nt], 0, 0, 0);
            }
        }
    }

    // ---- epilogue ----
    #pragma unroll
    for (int r = 0; r < 4; ++r) {
        float v = lsum[r];
        v += __shfl_xor(v, 1); v += __shfl_xor(v, 2);
        v += __shfl_xor(v, 4); v += __shfl_xor(v, 8);
        lsum[r] = (v > 0.f) ? 1.0f / v : 0.f;
    }
    #pragma unroll
    for (int nt = 0; nt < 4; ++nt) {
        #pragma unroll
        for (int r = 0; r < 4; ++r) {
            out[((qb + 4 * g + r) * NH + h) * DH + nt * 16 + c] = oacc[nt][r] * lsum[r];
        }
    }
}

extern "C" void kernel_launch(void* const* d_in, const int* in_sizes, int n_in,
                              void* d_out, int out_size, void* d_ws, size_t ws_size,
                              hipStream_t stream) {
    const float* Q    = (const float*)d_in[0];
    const float* K    = (const float*)d_in[1];
    const float* V    = (const float*)d_in[2];
    const void*  mask = d_in[3];
    float* out = (float*)d_out;

    const size_t need = 64 + (size_t)NWORDS * 8;
    if (ws_size >= need) {
        int*      flag = (int*)d_ws;
        uint64_t* bits = (uint64_t*)((char*)d_ws + 64);
        detect_kernel<<<1, 256, 0, stream>>>((const uint32_t*)mask, flag);
        pack_kernel<<<SEQ * SEQ / 256, 256, 0, stream>>>(mask, flag, bits);
        attn_mfma<true><<<dim3(NQT, NH), 256, 0, stream>>>(Q, K, V, bits, nullptr, out);
    } else {
        attn_mfma<false><<<dim3(NQT, NH), 256, 0, stream>>>(Q, K, V, nullptr,
                                                            (const int*)mask, out);
    }
}

// Round 3
// 151.695 us; speedup vs baseline: 5.8544x; 1.2177x over previous
//
#include <hip/hip_runtime.h>
#include <stdint.h>

#define SEQ 3072
#define NH  16
#define DH  64
#define QBLK 64
#define KVBLK 64
#define NKT (SEQ / KVBLK)   // 48
#define NQT (SEQ / QBLK)    // 48
#define NWORDS (SEQ * SEQ / 64)

typedef __attribute__((ext_vector_type(8))) __bf16 bf16x8;
typedef __attribute__((ext_vector_type(4))) float f32x4;

union BF8 { ushort us[8]; uint4 u4; bf16x8 v; };

__device__ __forceinline__ ushort f2bf(float f) {
    uint u = __builtin_bit_cast(uint, f);
    return (ushort)((u + 0x7FFFu + ((u >> 16) & 1u)) >> 16);
}

// ---------------- mask dtype detection ----------------
__global__ void detect_kernel(const uint32_t* __restrict__ m, int* __restrict__ flag) {
    __shared__ int cntA, cntB;
    if (threadIdx.x == 0) { cntA = 0; cntB = 0; }
    __syncthreads();
    int a = 0, b = 0;
    for (int i = 0; i < 16; ++i) {
        uint32_t w = m[threadIdx.x + i * 256];
        if (w & 0xFFFFFF00u) a = 1;
        if (w & 0x0000FFFFu) b = 1;
    }
    if (a) atomicOr(&cntA, 1);
    if (b) atomicOr(&cntB, 1);
    __syncthreads();
    if (threadIdx.x == 0) *flag = (cntA == 0) ? 1 : ((cntB == 0) ? 2 : 0);
}

// ---------------- mask -> bitmask pack ----------------
__global__ void pack_kernel(const void* __restrict__ mask, const int* __restrict__ flag,
                            uint64_t* __restrict__ bits) {
    int g = blockIdx.x * 256 + threadIdx.x;
    int f = *flag;
    bool v;
    if (f == 1)      v = ((const int*)mask)[g] != 0;
    else if (f == 2) v = ((const float*)mask)[g] != 0.0f;
    else             v = ((const unsigned char*)mask)[g] != 0;
    uint64_t b = __ballot(v);
    if ((threadIdx.x & 63) == 0) bits[g >> 6] = b;
}

// ---------------- Q convert: fp32 -> bf16 with scale*log2(e) folded ----------------
#define SCALE_Q (0.125f * 1.44269504f)
__global__ void convert_q(const float* __restrict__ Q, ushort* __restrict__ Qb) {
    int i = (blockIdx.x * 256 + threadIdx.x) * 8;
    float4 a = *(const float4*)(Q + i);
    float4 b = *(const float4*)(Q + i + 4);
    BF8 t;
    t.us[0] = f2bf(a.x * SCALE_Q); t.us[1] = f2bf(a.y * SCALE_Q);
    t.us[2] = f2bf(a.z * SCALE_Q); t.us[3] = f2bf(a.w * SCALE_Q);
    t.us[4] = f2bf(b.x * SCALE_Q); t.us[5] = f2bf(b.y * SCALE_Q);
    t.us[6] = f2bf(b.z * SCALE_Q); t.us[7] = f2bf(b.w * SCALE_Q);
    *(uint4*)(Qb + i) = t.u4;
}

// ---------------- K/V convert+swizzle pre-pass ----------------
// Output tile layout (per h,kt): 512 chunks of 8 bf16 (16B).
// K: chunk ch = row*8 + f'  holds  K[row][ (f'^(row&7))*8 + 0..7 ]
// Vt: chunk ch = d*8 + f'   holds  V[ (f'^(d&7))*8 + 0..7 ][d]
__global__ __launch_bounds__(256)
void convert_kv(const float* __restrict__ K, const float* __restrict__ V,
                ushort* __restrict__ Kbz, ushort* __restrict__ Vtz) {
    const int kt = blockIdx.x, h = blockIdx.y;
    const int tid = threadIdx.x;
    __shared__ float Vf[64][68];

    // stage V tile (coalesced) into LDS
    {
        const int kr = tid >> 2, dc = (tid & 3) * 16;
        const float* vsrc = V + (((size_t)(kt * KVBLK + kr) * NH + h) * DH + dc);
        #pragma unroll
        for (int j = 0; j < 4; ++j) {
            float4 t = *(const float4*)(vsrc + 4 * j);
            Vf[kr][dc + 4 * j + 0] = t.x; Vf[kr][dc + 4 * j + 1] = t.y;
            Vf[kr][dc + 4 * j + 2] = t.z; Vf[kr][dc + 4 * j + 3] = t.w;
        }
    }

    // K pass (independent of LDS)
    ushort* kout = Kbz + ((size_t)(h * NKT + kt)) * 4096;
    #pragma unroll
    for (int i = 0; i < 2; ++i) {
        const int ch = tid + 256 * i;
        const int r = ch >> 3, fp = ch & 7;
        const float* ks = K + (((size_t)(kt * KVBLK + r) * NH + h) * DH + (fp ^ (r & 7)) * 8);
        float4 a = *(const float4*)(ks);
        float4 b = *(const float4*)(ks + 4);
        BF8 t;
        t.us[0] = f2bf(a.x); t.us[1] = f2bf(a.y); t.us[2] = f2bf(a.z); t.us[3] = f2bf(a.w);
        t.us[4] = f2bf(b.x); t.us[5] = f2bf(b.y); t.us[6] = f2bf(b.z); t.us[7] = f2bf(b.w);
        *(uint4*)(kout + ch * 8) = t.u4;
    }

    __syncthreads();

    // Vt pass: transpose out of LDS
    ushort* vout = Vtz + ((size_t)(h * NKT + kt)) * 4096;
    #pragma unroll
    for (int i = 0; i < 2; ++i) {
        const int ch = tid + 256 * i;
        const int d = ch >> 3, fp = ch & 7;
        const int kc = fp ^ (d & 7);
        BF8 t;
        #pragma unroll
        for (int j = 0; j < 8; ++j)
            t.us[j] = f2bf(Vf[kc * 8 + j][d]);
        *(uint4*)(vout + ch * 8) = t.u4;
    }
}

// ---------------- MFMA flash attention (bf16 preconverted, dbuf staging) ----------------
__global__ __launch_bounds__(256, 2)
void attn3(const ushort* __restrict__ Qb, const ushort* __restrict__ Kbz,
           const ushort* __restrict__ Vtz, const uint64_t* __restrict__ bits,
           float* __restrict__ out)
{
    // XCD-chunked swizzle: 768 blocks, 8 XCDs -> 96 contiguous per XCD (2 heads)
    const int bid = blockIdx.x;
    const int swz = (bid & 7) * 96 + (bid >> 3);
    const int qtile = swz % NQT, h = swz / NQT;

    const int tid  = threadIdx.x;
    const int wv   = tid >> 6, lane = tid & 63;
    const int g    = lane >> 4, c = lane & 15;
    const int qb   = qtile * QBLK + wv * 16;

    __shared__ __align__(16) ushort KbS[2][4096];
    __shared__ __align__(16) ushort VtS[2][4096];
    __shared__ __align__(16) ushort PbS[4][16 * 72];
    ushort* Pw = &PbS[wv][0];

    // Q fragments (A-layout): row=c, k = kk*32 + g*8 + j
    bf16x8 qa[2];
    {
        const ushort* qp = Qb + ((size_t)(qb + c) * NH + h) * DH;
        qa[0] = *(const bf16x8*)(qp + g * 8);
        qa[1] = *(const bf16x8*)(qp + 32 + g * 8);
    }

    f32x4 oacc[4];
    float m_[4], lsum[4];
    #pragma unroll
    for (int nt = 0; nt < 4; ++nt) oacc[nt] = (f32x4){0.f, 0.f, 0.f, 0.f};
    #pragma unroll
    for (int r = 0; r < 4; ++r) { m_[r] = -1e30f; lsum[r] = 0.f; }

    const ushort* ktile = Kbz + ((size_t)h * NKT) * 4096;
    const ushort* vtile = Vtz + ((size_t)h * NKT) * 4096;

    uint4 kreg[2], vreg[2];
    // prologue: stage tile 0
    #pragma unroll
    for (int i = 0; i < 2; ++i) {
        kreg[i] = *(const uint4*)(ktile + (size_t)(tid + 256 * i) * 8);
        vreg[i] = *(const uint4*)(vtile + (size_t)(tid + 256 * i) * 8);
    }
    #pragma unroll
    for (int i = 0; i < 2; ++i) {
        *(uint4*)&KbS[0][(tid + 256 * i) * 8] = kreg[i];
        *(uint4*)&VtS[0][(tid + 256 * i) * 8] = vreg[i];
    }
    __syncthreads();

    int cur = 0;
    for (int kt = 0; kt < NKT; ++kt) {
        // issue next-tile loads early (latency hides under compute)
        if (kt + 1 < NKT) {
            const ushort* kn = ktile + (size_t)(kt + 1) * 4096;
            const ushort* vn = vtile + (size_t)(kt + 1) * 4096;
            #pragma unroll
            for (int i = 0; i < 2; ++i) {
                kreg[i] = *(const uint4*)(kn + (size_t)(tid + 256 * i) * 8);
                vreg[i] = *(const uint4*)(vn + (size_t)(tid + 256 * i) * 8);
            }
        }

        // mask words
        uint64_t mw[4];
        #pragma unroll
        for (int r = 0; r < 4; ++r)
            mw[r] = bits[(size_t)(qb + 4 * g + r) * NKT + kt];

        // ---- QK^T ----
        f32x4 sacc[4];
        #pragma unroll
        for (int nt = 0; nt < 4; ++nt) sacc[nt] = (f32x4){0.f, 0.f, 0.f, 0.f};
        #pragma unroll
        for (int kk = 0; kk < 2; ++kk) {
            #pragma unroll
            for (int nt = 0; nt < 4; ++nt) {
                const int krow = nt * 16 + c;
                bf16x8 kf = *(const bf16x8*)&KbS[cur][krow * 64 + ((4 * kk + g) ^ (krow & 7)) * 8];
                sacc[nt] = __builtin_amdgcn_mfma_f32_16x16x32_bf16(qa[kk], kf, sacc[nt], 0, 0, 0);
            }
        }

        // ---- mask + row max ----
        float pmax[4];
        #pragma unroll
        for (int r = 0; r < 4; ++r) pmax[r] = -1e30f;
        #pragma unroll
        for (int nt = 0; nt < 4; ++nt) {
            #pragma unroll
            for (int r = 0; r < 4; ++r) {
                bool keep = (mw[r] >> (nt * 16 + c)) & 1ull;
                float s = keep ? sacc[nt][r] : -1e30f;
                sacc[nt][r] = s;
                pmax[r] = fmaxf(pmax[r], s);
            }
        }
        #pragma unroll
        for (int r = 0; r < 4; ++r) {
            float v = pmax[r];
            v = fmaxf(v, __shfl_xor(v, 1));
            v = fmaxf(v, __shfl_xor(v, 2));
            v = fmaxf(v, __shfl_xor(v, 4));
            v = fmaxf(v, __shfl_xor(v, 8));
            pmax[r] = v;
        }
        // ---- defer-max rescale (log2 domain, THR=11 ~ e^7.6) ----
        bool need = false;
        #pragma unroll
        for (int r = 0; r < 4; ++r) need |= (pmax[r] > m_[r] + 11.0f);
        if (__any(need)) {
            #pragma unroll
            for (int r = 0; r < 4; ++r) {
                float nm = fmaxf(m_[r], pmax[r]);
                float al = exp2f(m_[r] - nm);
                m_[r] = nm;
                lsum[r] *= al;
                #pragma unroll
                for (int nt = 0; nt < 4; ++nt) oacc[nt][r] *= al;
            }
        }
        // ---- P = exp2(s-m) -> per-wave LDS (swizzled row-major) ----
        #pragma unroll
        for (int nt = 0; nt < 4; ++nt) {
            #pragma unroll
            for (int r = 0; r < 4; ++r) {
                float p = exp2f(sacc[nt][r] - m_[r]);
                lsum[r] += p;
                const int row = 4 * g + r, col = nt * 16 + c;
                Pw[row * 72 + (((col >> 3) ^ (row & 7))) * 8 + (col & 7)] = f2bf(p);
            }
        }
        // ---- PV ----
        #pragma unroll
        for (int kk = 0; kk < 2; ++kk) {
            bf16x8 pa = *(const bf16x8*)&Pw[c * 72 + ((4 * kk + g) ^ (c & 7)) * 8];
            #pragma unroll
            for (int nt = 0; nt < 4; ++nt) {
                const int d = nt * 16 + c;
                bf16x8 vb = *(const bf16x8*)&VtS[cur][d * 64 + ((4 * kk + g) ^ (d & 7)) * 8];
                oacc[nt] = __builtin_amdgcn_mfma_f32_16x16x32_bf16(pa, vb, oacc[nt], 0, 0, 0);
            }
        }

        // write staged regs into the other buffer, then barrier
        if (kt + 1 < NKT) {
            #pragma unroll
            for (int i = 0; i < 2; ++i) {
                *(uint4*)&KbS[cur ^ 1][(tid + 256 * i) * 8] = kreg[i];
                *(uint4*)&VtS[cur ^ 1][(tid + 256 * i) * 8] = vreg[i];
            }
        }
        __syncthreads();
        cur ^= 1;
    }

    // ---- epilogue ----
    #pragma unroll
    for (int r = 0; r < 4; ++r) {
        float v = lsum[r];
        v += __shfl_xor(v, 1); v += __shfl_xor(v, 2);
        v += __shfl_xor(v, 4); v += __shfl_xor(v, 8);
        lsum[r] = (v > 0.f) ? 1.0f / v : 0.f;
    }
    #pragma unroll
    for (int nt = 0; nt < 4; ++nt) {
        #pragma unroll
        for (int r = 0; r < 4; ++r) {
            out[((size_t)(qb + 4 * g + r) * NH + h) * DH + nt * 16 + c] = oacc[nt][r] * lsum[r];
        }
    }
}

// ---------------- fallback (R2 kernel, direct int32 mask) ----------------
__global__ __launch_bounds__(256, 2)
void attn_fb(const float* __restrict__ Q, const float* __restrict__ K,
             const float* __restrict__ V, const int* __restrict__ mask_i32,
             float* __restrict__ out)
{
    const int qtile = blockIdx.x, h = blockIdx.y;
    const int tid  = threadIdx.x;
    const int wv   = tid >> 6, lane = tid & 63;
    const int g    = lane >> 4, c = lane & 15;
    const int qb   = qtile * QBLK + wv * 16;

    __shared__ __align__(16) ushort KbS[KVBLK * 72];
    __shared__ __align__(16) ushort VtS[DH * 72];
    __shared__ __align__(16) ushort PbS[4 * 16 * 72];
    ushort* Pw = &PbS[wv * 16 * 72];

    bf16x8 qa[2];
    {
        const float* qp = Q + ((qb + c) * NH + h) * DH;
        #pragma unroll
        for (int kk = 0; kk < 2; ++kk) {
            BF8 t;
            const float4* p = (const float4*)(qp + kk * 32 + g * 8);
            float4 f0 = p[0], f1 = p[1];
            t.us[0] = f2bf(f0.x * 0.125f); t.us[1] = f2bf(f0.y * 0.125f);
            t.us[2] = f2bf(f0.z * 0.125f); t.us[3] = f2bf(f0.w * 0.125f);
            t.us[4] = f2bf(f1.x * 0.125f); t.us[5] = f2bf(f1.y * 0.125f);
            t.us[6] = f2bf(f1.z * 0.125f); t.us[7] = f2bf(f1.w * 0.125f);
            qa[kk] = t.v;
        }
    }

    f32x4 oacc[4];
    float m_[4], lsum[4];
    #pragma unroll
    for (int nt = 0; nt < 4; ++nt) oacc[nt] = (f32x4){0.f, 0.f, 0.f, 0.f};
    #pragma unroll
    for (int r = 0; r < 4; ++r) { m_[r] = -1e30f; lsum[r] = 0.f; }

    const int srow0 = tid >> 3;
    const int fch   = tid & 7;

    for (int kt = 0; kt < NKT; ++kt) {
        __syncthreads();
        #pragma unroll
        for (int i = 0; i < 2; ++i) {
            const int krow = srow0 + 32 * i;
            const int gofs = ((kt * KVBLK + krow) * NH + h) * DH + fch * 8;
            const float4* kp = (const float4*)(K + gofs);
            const float4* vp = (const float4*)(V + gofs);
            float4 k0 = kp[0], k1 = kp[1];
            float4 v0 = vp[0], v1 = vp[1];
            BF8 kb;
            kb.us[0] = f2bf(k0.x); kb.us[1] = f2bf(k0.y);
            kb.us[2] = f2bf(k0.z); kb.us[3] = f2bf(k0.w);
            kb.us[4] = f2bf(k1.x); kb.us[5] = f2bf(k1.y);
            kb.us[6] = f2bf(k1.z); kb.us[7] = f2bf(k1.w);
            *(uint4*)&KbS[krow * 72 + (fch ^ (krow & 7)) * 8] = kb.u4;
            float vf[8] = {v0.x, v0.y, v0.z, v0.w, v1.x, v1.y, v1.z, v1.w};
            #pragma unroll
            for (int j = 0; j < 8; ++j) {
                const int d = fch * 8 + j;
                VtS[d * 72 + ((krow >> 3) ^ ((d >> 3) & 7)) * 8 + (krow & 7)] = f2bf(vf[j]);
            }
        }
        __syncthreads();

        f32x4 sacc[4];
        #pragma unroll
        for (int nt = 0; nt < 4; ++nt) sacc[nt] = (f32x4){0.f, 0.f, 0.f, 0.f};
        #pragma unroll
        for (int kk = 0; kk < 2; ++kk) {
            #pragma unroll
            for (int nt = 0; nt < 4; ++nt) {
                const int krow = nt * 16 + c;
                bf16x8 kf = *(const bf16x8*)&KbS[krow * 72 + (((g + 4 * kk) ^ (krow & 7))) * 8];
                sacc[nt] = __builtin_amdgcn_mfma_f32_16x16x32_bf16(qa[kk], kf, sacc[nt], 0, 0, 0);
            }
        }

        float pmax[4];
        #pragma unroll
        for (int r = 0; r < 4; ++r) pmax[r] = -1e30f;
        #pragma unroll
        for (int nt = 0; nt < 4; ++nt) {
            #pragma unroll
            for (int r = 0; r < 4; ++r) {
                bool keep = mask_i32[(size_t)(qb + 4 * g + r) * SEQ + kt * KVBLK + nt * 16 + c] != 0;
                float s = keep ? sacc[nt][r] : -1e30f;
                sacc[nt][r] = s;
                pmax[r] = fmaxf(pmax[r], s);
            }
        }
        #pragma unroll
        for (int r = 0; r < 4; ++r) {
            float v = pmax[r];
            v = fmaxf(v, __shfl_xor(v, 1));
            v = fmaxf(v, __shfl_xor(v, 2));
            v = fmaxf(v, __shfl_xor(v, 4));
            v = fmaxf(v, __shfl_xor(v, 8));
            float nm = fmaxf(m_[r], v);
            float alpha = __expf(m_[r] - nm);
            m_[r] = nm;
            lsum[r] *= alpha;
            #pragma unroll
            for (int nt = 0; nt < 4; ++nt) oacc[nt][r] *= alpha;
        }
        #pragma unroll
        for (int nt = 0; nt < 4; ++nt) {
            #pragma unroll
            for (int r = 0; r < 4; ++r) {
                float p = __expf(sacc[nt][r] - m_[r]);
                lsum[r] += p;
                const int row = 4 * g + r, col = nt * 16 + c;
                Pw[row * 72 + (((col >> 3) ^ (row & 7))) * 8 + (col & 7)] = f2bf(p);
            }
        }
        #pragma unroll
        for (int kk = 0; kk < 2; ++kk) {
            bf16x8 pa = *(const bf16x8*)&Pw[c * 72 + (((g + 4 * kk) ^ (c & 7))) * 8];
            #pragma unroll
            for (int nt = 0; nt < 4; ++nt) {
                const int d = nt * 16 + c;
                bf16x8 vb = *(const bf16x8*)&VtS[d * 72 + (((g + 4 * kk) ^ ((d >> 3) & 7))) * 8];
                oacc[nt] = __builtin_amdgcn_mfma_f32_16x16x32_bf16(pa, vb, oacc[nt], 0, 0, 0);
            }
        }
    }

    #pragma unroll
    for (int r = 0; r < 4; ++r) {
        float v = lsum[r];
        v += __shfl_xor(v, 1); v += __shfl_xor(v, 2);
        v += __shfl_xor(v, 4); v += __shfl_xor(v, 8);
        lsum[r] = (v > 0.f) ? 1.0f / v : 0.f;
    }
    #pragma unroll
    for (int nt = 0; nt < 4; ++nt) {
        #pragma unroll
        for (int r = 0; r < 4; ++r) {
            out[((qb + 4 * g + r) * NH + h) * DH + nt * 16 + c] = oacc[nt][r] * lsum[r];
        }
    }
}

extern "C" void kernel_launch(void* const* d_in, const int* in_sizes, int n_in,
                              void* d_out, int out_size, void* d_ws, size_t ws_size,
                              hipStream_t stream) {
    const float* Q    = (const float*)d_in[0];
    const float* K    = (const float*)d_in[1];
    const float* V    = (const float*)d_in[2];
    const void*  mask = d_in[3];
    float* out = (float*)d_out;

    // ws layout
    const size_t off_bits = 64;
    const size_t off_qb   = off_bits + (size_t)NWORDS * 8;              // 1179712
    const size_t off_kbz  = off_qb  + (size_t)SEQ * NH * DH * 2;        // +6291456
    const size_t off_vtz  = off_kbz + (size_t)SEQ * NH * DH * 2;
    const size_t need     = off_vtz + (size_t)SEQ * NH * DH * 2;

    if (ws_size >= need) {
        int*      flag = (int*)d_ws;
        uint64_t* bits = (uint64_t*)((char*)d_ws + off_bits);
        ushort*   Qb   = (ushort*)((char*)d_ws + off_qb);
        ushort*   Kbz  = (ushort*)((char*)d_ws + off_kbz);
        ushort*   Vtz  = (ushort*)((char*)d_ws + off_vtz);
        detect_kernel<<<1, 256, 0, stream>>>((const uint32_t*)mask, flag);
        pack_kernel<<<SEQ * SEQ / 256, 256, 0, stream>>>(mask, flag, bits);
        convert_q<<<SEQ * NH * DH / (256 * 8), 256, 0, stream>>>(Q, Qb);
        convert_kv<<<dim3(NKT, NH), 256, 0, stream>>>(K, V, Kbz, Vtz);
        attn3<<<NQT * NH, 256, 0, stream>>>(Qb, Kbz, Vtz, bits, out);
    } else {
        attn_fb<<<dim3(NQT, NH), 256, 0, stream>>>(Q, K, V, (const int*)mask, out);
    }
}

// Round 5
// 123.067 us; speedup vs baseline: 7.2162x; 1.2326x over previous
//
#include <hip/hip_runtime.h>
#include <stdint.h>

#define SEQ 3072
#define NH  16
#define DH  64
#define WQ  32               // q rows per wave
#define NWAVE 4
#define QBLK (WQ * NWAVE)    // 128
#define KVBLK 64
#define NKT (SEQ / KVBLK)    // 48
#define NQB (SEQ / QBLK)     // 24
#define NWORDS (SEQ * SEQ / 64)

typedef __attribute__((ext_vector_type(8))) __bf16 bf16x8;
typedef __attribute__((ext_vector_type(16))) float f32x16;

union BF8 { ushort us[8]; uint u[4]; uint4 u4; bf16x8 v; };

__device__ __forceinline__ ushort f2bf(float f) {
    uint u = __builtin_bit_cast(uint, f);
    return (ushort)((u + 0x7FFFu + ((u >> 16) & 1u)) >> 16);
}

// ---------------- mask dtype detection ----------------
__global__ void detect_kernel(const uint32_t* __restrict__ m, int* __restrict__ flag) {
    __shared__ int cntA, cntB;
    if (threadIdx.x == 0) { cntA = 0; cntB = 0; }
    __syncthreads();
    int a = 0, b = 0;
    for (int i = 0; i < 16; ++i) {
        uint32_t w = m[threadIdx.x + i * 256];
        if (w & 0xFFFFFF00u) a = 1;
        if (w & 0x0000FFFFu) b = 1;
    }
    if (a) atomicOr(&cntA, 1);
    if (b) atomicOr(&cntB, 1);
    __syncthreads();
    if (threadIdx.x == 0) *flag = (cntA == 0) ? 1 : ((cntB == 0) ? 2 : 0);
}

// ---------------- mask -> transposed bitmask: bits2[kword*SEQ + qrow] ----------------
__global__ void pack_kernel(const void* __restrict__ mask, const int* __restrict__ flag,
                            uint64_t* __restrict__ bits) {
    int g = blockIdx.x * 256 + threadIdx.x;
    int f = *flag;
    bool v;
    if (f == 1)      v = ((const int*)mask)[g] != 0;
    else if (f == 2) v = ((const float*)mask)[g] != 0.0f;
    else             v = ((const unsigned char*)mask)[g] != 0;
    uint64_t b = __ballot(v);
    if ((threadIdx.x & 63) == 0) {
        int w = g >> 6;
        int qrow = w / NKT, cw = w % NKT;
        bits[(size_t)cw * SEQ + qrow] = b;
    }
}

// ---------------- Q convert: fp32 -> bf16, scale*log2(e) folded ----------------
#define SCALE_Q (0.125f * 1.44269504f)
__global__ void convert_q(const float* __restrict__ Q, ushort* __restrict__ Qb) {
    int i = (blockIdx.x * 256 + threadIdx.x) * 8;
    float4 a = *(const float4*)(Q + i);
    float4 b = *(const float4*)(Q + i + 4);
    BF8 t;
    t.us[0] = f2bf(a.x * SCALE_Q); t.us[1] = f2bf(a.y * SCALE_Q);
    t.us[2] = f2bf(a.z * SCALE_Q); t.us[3] = f2bf(a.w * SCALE_Q);
    t.us[4] = f2bf(b.x * SCALE_Q); t.us[5] = f2bf(b.y * SCALE_Q);
    t.us[6] = f2bf(b.z * SCALE_Q); t.us[7] = f2bf(b.w * SCALE_Q);
    *(uint4*)(Qb + i) = t.u4;
}

// ---------------- K/V convert+swizzle pre-pass ----------------
// K tile: chunk ch = row*8 + f' holds K[row][(f'^(row&7))*8 + 0..7]
// Vt tile: chunk ch = d*8 + f'  holds V[(f'^(d&7))*8 + 0..7][d]
__global__ __launch_bounds__(256)
void convert_kv(const float* __restrict__ K, const float* __restrict__ V,
                ushort* __restrict__ Kbz, ushort* __restrict__ Vtz) {
    const int kt = blockIdx.x, h = blockIdx.y;
    const int tid = threadIdx.x;
    __shared__ float Vf[64][68];

    {
        const int kr = tid >> 2, dc = (tid & 3) * 16;
        const float* vsrc = V + (((size_t)(kt * KVBLK + kr) * NH + h) * DH + dc);
        #pragma unroll
        for (int j = 0; j < 4; ++j) {
            float4 t = *(const float4*)(vsrc + 4 * j);
            Vf[kr][dc + 4 * j + 0] = t.x; Vf[kr][dc + 4 * j + 1] = t.y;
            Vf[kr][dc + 4 * j + 2] = t.z; Vf[kr][dc + 4 * j + 3] = t.w;
        }
    }

    ushort* kout = Kbz + ((size_t)(h * NKT + kt)) * 4096;
    #pragma unroll
    for (int i = 0; i < 2; ++i) {
        const int ch = tid + 256 * i;
        const int r = ch >> 3, fp = ch & 7;
        const float* ks = K + (((size_t)(kt * KVBLK + r) * NH + h) * DH + (fp ^ (r & 7)) * 8);
        float4 a = *(const float4*)(ks);
        float4 b = *(const float4*)(ks + 4);
        BF8 t;
        t.us[0] = f2bf(a.x); t.us[1] = f2bf(a.y); t.us[2] = f2bf(a.z); t.us[3] = f2bf(a.w);
        t.us[4] = f2bf(b.x); t.us[5] = f2bf(b.y); t.us[6] = f2bf(b.z); t.us[7] = f2bf(b.w);
        *(uint4*)(kout + ch * 8) = t.u4;
    }

    __syncthreads();

    ushort* vout = Vtz + ((size_t)(h * NKT + kt)) * 4096;
    #pragma unroll
    for (int i = 0; i < 2; ++i) {
        const int ch = tid + 256 * i;
        const int d = ch >> 3, fp = ch & 7;
        const int kc = fp ^ (d & 7);
        BF8 t;
        #pragma unroll
        for (int j = 0; j < 8; ++j)
            t.us[j] = f2bf(Vf[kc * 8 + j][d]);
        *(uint4*)(vout + ch * 8) = t.u4;
    }
}

// ---------------- MFMA flash attention: swapped QK^T, in-register softmax ----------------
// S = mfma(A=K, B=Q): D col = lane&31 = q, D rows = k-slot (r&3)+8*(r>>2)+4*hh.
// O = mfma(A=P, B=Vt): D col = lane&31 = d, D rows = q.
// v_permlane32_swap_b32 vdst, vsrc: new dst = [dst_lo | src_lo], new src = [dst_hi | src_hi].
__global__ __launch_bounds__(256, 2)
void attn4(const ushort* __restrict__ Qb, const ushort* __restrict__ Kbz,
           const ushort* __restrict__ Vtz, const uint64_t* __restrict__ bits2,
           float* __restrict__ out)
{
    const int bid = blockIdx.x;
    const int swz = (bid & 7) * (NQB * NH / 8) + (bid >> 3);
    const int h = swz / NQB, qt = swz % NQB;
    const int tid = threadIdx.x;
    const int wv = tid >> 6, lane = tid & 63;
    const int lq = lane & 31, hh = lane >> 5;
    const int qrow0 = qt * QBLK + wv * WQ;

    __shared__ __align__(16) ushort KbS[2][4096];
    __shared__ __align__(16) ushort VtS[2][4096];

    // Q B-frags: qf[kc] = Q[qrow0+lq][kc*16 + hh*8 + j]
    bf16x8 qf[4];
    {
        const ushort* qp = Qb + ((size_t)(qrow0 + lq) * NH + h) * DH;
        #pragma unroll
        for (int kc = 0; kc < 4; ++kc)
            qf[kc] = *(const bf16x8*)(qp + kc * 16 + hh * 8);
    }

    f32x16 o0, o1;
    #pragma unroll
    for (int i = 0; i < 16; ++i) { o0[i] = 0.f; o1[i] = 0.f; }
    float m_ = 0.0f, l_ = 0.0f;   // log2 domain, deferred max (m starts 0)

    const ushort* ktile = Kbz + (size_t)h * NKT * 4096;
    const ushort* vtile = Vtz + (size_t)h * NKT * 4096;

    uint4 kreg[2], vreg[2];
    #pragma unroll
    for (int i = 0; i < 2; ++i) {
        kreg[i] = *(const uint4*)(ktile + (size_t)(tid + 256 * i) * 8);
        vreg[i] = *(const uint4*)(vtile + (size_t)(tid + 256 * i) * 8);
    }
    #pragma unroll
    for (int i = 0; i < 2; ++i) {
        *(uint4*)&KbS[0][(tid + 256 * i) * 8] = kreg[i];
        *(uint4*)&VtS[0][(tid + 256 * i) * 8] = vreg[i];
    }
    __syncthreads();

    int cur = 0;
    for (int kt = 0; kt < NKT; ++kt) {
        // T14: issue next-tile global loads early
        if (kt + 1 < NKT) {
            const ushort* kn = ktile + (size_t)(kt + 1) * 4096;
            const ushort* vn = vtile + (size_t)(kt + 1) * 4096;
            #pragma unroll
            for (int i = 0; i < 2; ++i) {
                kreg[i] = *(const uint4*)(kn + (size_t)(tid + 256 * i) * 8);
                vreg[i] = *(const uint4*)(vn + (size_t)(tid + 256 * i) * 8);
            }
        }
        const uint64_t mw = bits2[(size_t)kt * SEQ + qrow0 + lq];

        // ---- QK^T ----
        f32x16 s0, s1;
        #pragma unroll
        for (int i = 0; i < 16; ++i) { s0[i] = 0.f; s1[i] = 0.f; }
        __builtin_amdgcn_s_setprio(1);
        #pragma unroll
        for (int kc = 0; kc < 4; ++kc) {
            const int f0 = (hh + 2 * kc) ^ (lq & 7);
            bf16x8 k0 = *(const bf16x8*)&KbS[cur][lq * 64 + f0 * 8];
            s0 = __builtin_amdgcn_mfma_f32_32x32x16_bf16(k0, qf[kc], s0, 0, 0, 0);
            bf16x8 k1 = *(const bf16x8*)&KbS[cur][(lq + 32) * 64 + f0 * 8];
            s1 = __builtin_amdgcn_mfma_f32_32x32x16_bf16(k1, qf[kc], s1, 0, 0, 0);
        }
        __builtin_amdgcn_s_setprio(0);

        // ---- in-register softmax (per-lane q = lq) ----
        const uint64_t mu = mw >> (4 * hh);
        const uint mlo = (uint)mu, mhi = (uint)(mu >> 32);

        float pm = -1e30f;
        #pragma unroll
        for (int i = 0; i < 16; ++i) pm = fmaxf(pm, fmaxf(s0[i], s1[i]));
        {   // cross-half max (direction-invariant use of the swap)
            float a = pm, b = pm;
            asm("v_permlane32_swap_b32 %0, %1" : "+v"(a), "+v"(b));
            pm = fmaxf(a, b);
        }

        // T13 defer-max: rare path (m starts at 0; scores in log2 units, max ~6)
        if (__any(pm > m_ + 12.0f)) {
            const float mnew = fmaxf(m_, pm);
            const float alpha = __builtin_amdgcn_exp2f(m_ - mnew);
            l_ *= alpha;
            #pragma unroll
            for (int r = 0; r < 16; ++r) {
                const int q_r = (r & 3) + 8 * (r >> 2) + 4 * hh;
                const float ar = __shfl(alpha, q_r);
                o0[r] *= ar; o1[r] *= ar;
            }
            m_ = mnew;
        }

        // p = exp2(s - m) * maskbit
        float lacc = 0.f;
        #pragma unroll
        for (int r = 0; r < 16; ++r) {
            const int sh = (r & 3) + 8 * (r >> 2);
            float p0 = __builtin_amdgcn_exp2f(s0[r] - m_);
            p0 = ((mlo >> sh) & 1u) ? p0 : 0.f;
            float p1 = __builtin_amdgcn_exp2f(s1[r] - m_);
            p1 = ((mhi >> sh) & 1u) ? p1 : 0.f;
            s0[r] = p0; s1[r] = p1;
            lacc += p0 + p1;
        }
        l_ += lacc;

        // ---- T12: P -> bf16 A-frags via cvt_pk + permlane32_swap ----
        // wl = low-k pack (dst), wh = high-k pack (src):
        // after swap: wl = [wl_lo|wh_lo] (= frag u_lo), wh = [wl_hi|wh_hi] (= frag u_hi)
        bf16x8 pa[4];
        {
            #define PKSWAP(dlo, dhi, a0, a1, b0, b1)                                   \
                {   uint wl, wh;                                                       \
                    asm("v_cvt_pk_bf16_f32 %0, %1, %2" : "=v"(wl) : "v"(a0), "v"(a1)); \
                    asm("v_cvt_pk_bf16_f32 %0, %1, %2" : "=v"(wh) : "v"(b0), "v"(b1)); \
                    asm("v_permlane32_swap_b32 %0, %1" : "+v"(wl), "+v"(wh));          \
                    dlo = wl; dhi = wh; }
            BF8 t0, t1, t2, t3;
            PKSWAP(t0.u[0], t0.u[2], s0[0],  s0[1],  s0[4],  s0[5]);
            PKSWAP(t0.u[1], t0.u[3], s0[2],  s0[3],  s0[6],  s0[7]);
            PKSWAP(t1.u[0], t1.u[2], s0[8],  s0[9],  s0[12], s0[13]);
            PKSWAP(t1.u[1], t1.u[3], s0[10], s0[11], s0[14], s0[15]);
            PKSWAP(t2.u[0], t2.u[2], s1[0],  s1[1],  s1[4],  s1[5]);
            PKSWAP(t2.u[1], t2.u[3], s1[2],  s1[3],  s1[6],  s1[7]);
            PKSWAP(t3.u[0], t3.u[2], s1[8],  s1[9],  s1[12], s1[13]);
            PKSWAP(t3.u[1], t3.u[3], s1[10], s1[11], s1[14], s1[15]);
            pa[0] = t0.v; pa[1] = t1.v; pa[2] = t2.v; pa[3] = t3.v;
            #undef PKSWAP
        }

        // ---- PV ----
        __builtin_amdgcn_s_setprio(1);
        #pragma unroll
        for (int kc = 0; kc < 4; ++kc) {
            const int f0 = (hh + 2 * kc) ^ (lq & 7);
            bf16x8 v0 = *(const bf16x8*)&VtS[cur][lq * 64 + f0 * 8];
            o0 = __builtin_amdgcn_mfma_f32_32x32x16_bf16(pa[kc], v0, o0, 0, 0, 0);
            bf16x8 v1 = *(const bf16x8*)&VtS[cur][(lq + 32) * 64 + f0 * 8];
            o1 = __builtin_amdgcn_mfma_f32_32x32x16_bf16(pa[kc], v1, o1, 0, 0, 0);
        }
        __builtin_amdgcn_s_setprio(0);

        // T14: late LDS write of prefetched tile, one barrier per tile
        if (kt + 1 < NKT) {
            #pragma unroll
            for (int i = 0; i < 2; ++i) {
                *(uint4*)&KbS[cur ^ 1][(tid + 256 * i) * 8] = kreg[i];
                *(uint4*)&VtS[cur ^ 1][(tid + 256 * i) * 8] = vreg[i];
            }
        }
        __syncthreads();
        cur ^= 1;
    }

    // ---- epilogue ----
    {
        float a = l_, b = l_;
        asm("v_permlane32_swap_b32 %0, %1" : "+v"(a), "+v"(b));
        l_ = a + b;
    }
    const float inv = (l_ > 0.f) ? 1.0f / l_ : 0.f;
    #pragma unroll
    for (int r = 0; r < 16; ++r) {
        const int q_r = (r & 3) + 8 * (r >> 2) + 4 * hh;
        const float ir = __shfl(inv, q_r);
        float* op = out + ((size_t)(qrow0 + q_r) * NH + h) * DH;
        op[lq]      = o0[r] * ir;
        op[lq + 32] = o1[r] * ir;
    }
}

// ---------------- fallback (direct int32 mask; only if ws too small) ----------------
__global__ __launch_bounds__(256, 2)
void attn_fb(const float* __restrict__ Q, const float* __restrict__ K,
             const float* __restrict__ V, const int* __restrict__ mask_i32,
             float* __restrict__ out)
{
    const int qtile = blockIdx.x, h = blockIdx.y;
    const int tid  = threadIdx.x;
    const int wv   = tid >> 6, lane = tid & 63;
    const int g    = lane >> 4, c = lane & 15;
    const int qb   = qtile * 64 + wv * 16;

    typedef __attribute__((ext_vector_type(4))) float f32x4;
    __shared__ __align__(16) ushort KbS[KVBLK * 72];
    __shared__ __align__(16) ushort VtS[DH * 72];
    __shared__ __align__(16) ushort PbS[4 * 16 * 72];
    ushort* Pw = &PbS[wv * 16 * 72];

    bf16x8 qa[2];
    {
        const float* qp = Q + ((qb + c) * NH + h) * DH;
        #pragma unroll
        for (int kk = 0; kk < 2; ++kk) {
            BF8 t;
            const float4* p = (const float4*)(qp + kk * 32 + g * 8);
            float4 f0 = p[0], f1 = p[1];
            t.us[0] = f2bf(f0.x * 0.125f); t.us[1] = f2bf(f0.y * 0.125f);
            t.us[2] = f2bf(f0.z * 0.125f); t.us[3] = f2bf(f0.w * 0.125f);
            t.us[4] = f2bf(f1.x * 0.125f); t.us[5] = f2bf(f1.y * 0.125f);
            t.us[6] = f2bf(f1.z * 0.125f); t.us[7] = f2bf(f1.w * 0.125f);
            qa[kk] = t.v;
        }
    }

    f32x4 oacc[4];
    float m_[4], lsum[4];
    #pragma unroll
    for (int nt = 0; nt < 4; ++nt) oacc[nt] = (f32x4){0.f, 0.f, 0.f, 0.f};
    #pragma unroll
    for (int r = 0; r < 4; ++r) { m_[r] = -1e30f; lsum[r] = 0.f; }

    const int srow0 = tid >> 3;
    const int fch   = tid & 7;

    for (int kt = 0; kt < NKT; ++kt) {
        __syncthreads();
        #pragma unroll
        for (int i = 0; i < 2; ++i) {
            const int krow = srow0 + 32 * i;
            const int gofs = ((kt * KVBLK + krow) * NH + h) * DH + fch * 8;
            const float4* kp = (const float4*)(K + gofs);
            const float4* vp = (const float4*)(V + gofs);
            float4 k0 = kp[0], k1 = kp[1];
            float4 v0 = vp[0], v1 = vp[1];
            BF8 kb;
            kb.us[0] = f2bf(k0.x); kb.us[1] = f2bf(k0.y);
            kb.us[2] = f2bf(k0.z); kb.us[3] = f2bf(k0.w);
            kb.us[4] = f2bf(k1.x); kb.us[5] = f2bf(k1.y);
            kb.us[6] = f2bf(k1.z); kb.us[7] = f2bf(k1.w);
            *(uint4*)&KbS[krow * 72 + (fch ^ (krow & 7)) * 8] = kb.u4;
            float vf[8] = {v0.x, v0.y, v0.z, v0.w, v1.x, v1.y, v1.z, v1.w};
            #pragma unroll
            for (int j = 0; j < 8; ++j) {
                const int d = fch * 8 + j;
                VtS[d * 72 + ((krow >> 3) ^ ((d >> 3) & 7)) * 8 + (krow & 7)] = f2bf(vf[j]);
            }
        }
        __syncthreads();

        f32x4 sacc[4];
        #pragma unroll
        for (int nt = 0; nt < 4; ++nt) sacc[nt] = (f32x4){0.f, 0.f, 0.f, 0.f};
        #pragma unroll
        for (int kk = 0; kk < 2; ++kk) {
            #pragma unroll
            for (int nt = 0; nt < 4; ++nt) {
                const int krow = nt * 16 + c;
                bf16x8 kf = *(const bf16x8*)&KbS[krow * 72 + (((g + 4 * kk) ^ (krow & 7))) * 8];
                sacc[nt] = __builtin_amdgcn_mfma_f32_16x16x32_bf16(qa[kk], kf, sacc[nt], 0, 0, 0);
            }
        }

        float pmax[4];
        #pragma unroll
        for (int r = 0; r < 4; ++r) pmax[r] = -1e30f;
        #pragma unroll
        for (int nt = 0; nt < 4; ++nt) {
            #pragma unroll
            for (int r = 0; r < 4; ++r) {
                bool keep = mask_i32[(size_t)(qb + 4 * g + r) * SEQ + kt * KVBLK + nt * 16 + c] != 0;
                float s = keep ? sacc[nt][r] : -1e30f;
                sacc[nt][r] = s;
                pmax[r] = fmaxf(pmax[r], s);
            }
        }
        #pragma unroll
        for (int r = 0; r < 4; ++r) {
            float v = pmax[r];
            v = fmaxf(v, __shfl_xor(v, 1));
            v = fmaxf(v, __shfl_xor(v, 2));
            v = fmaxf(v, __shfl_xor(v, 4));
            v = fmaxf(v, __shfl_xor(v, 8));
            float nm = fmaxf(m_[r], v);
            float alpha = __expf(m_[r] - nm);
            m_[r] = nm;
            lsum[r] *= alpha;
            #pragma unroll
            for (int nt = 0; nt < 4; ++nt) oacc[nt][r] *= alpha;
        }
        #pragma unroll
        for (int nt = 0; nt < 4; ++nt) {
            #pragma unroll
            for (int r = 0; r < 4; ++r) {
                float p = __expf(sacc[nt][r] - m_[r]);
                lsum[r] += p;
                const int row = 4 * g + r, col = nt * 16 + c;
                Pw[row * 72 + (((col >> 3) ^ (row & 7))) * 8 + (col & 7)] = f2bf(p);
            }
        }
        #pragma unroll
        for (int kk = 0; kk < 2; ++kk) {
            bf16x8 pa = *(const bf16x8*)&Pw[c * 72 + (((g + 4 * kk) ^ (c & 7))) * 8];
            #pragma unroll
            for (int nt = 0; nt < 4; ++nt) {
                const int d = nt * 16 + c;
                bf16x8 vb = *(const bf16x8*)&VtS[d * 72 + (((g + 4 * kk) ^ ((d >> 3) & 7))) * 8];
                oacc[nt] = __builtin_amdgcn_mfma_f32_16x16x32_bf16(pa, vb, oacc[nt], 0, 0, 0);
            }
        }
    }

    #pragma unroll
    for (int r = 0; r < 4; ++r) {
        float v = lsum[r];
        v += __shfl_xor(v, 1); v += __shfl_xor(v, 2);
        v += __shfl_xor(v, 4); v += __shfl_xor(v, 8);
        lsum[r] = (v > 0.f) ? 1.0f / v : 0.f;
    }
    #pragma unroll
    for (int nt = 0; nt < 4; ++nt) {
        #pragma unroll
        for (int r = 0; r < 4; ++r) {
            out[((qb + 4 * g + r) * NH + h) * DH + nt * 16 + c] = oacc[nt][r] * lsum[r];
        }
    }
}

extern "C" void kernel_launch(void* const* d_in, const int* in_sizes, int n_in,
                              void* d_out, int out_size, void* d_ws, size_t ws_size,
                              hipStream_t stream) {
    const float* Q    = (const float*)d_in[0];
    const float* K    = (const float*)d_in[1];
    const float* V    = (const float*)d_in[2];
    const void*  mask = d_in[3];
    float* out = (float*)d_out;

    const size_t off_bits = 64;
    const size_t off_qb   = off_bits + (size_t)NWORDS * 8;
    const size_t off_kbz  = off_qb  + (size_t)SEQ * NH * DH * 2;
    const size_t off_vtz  = off_kbz + (size_t)SEQ * NH * DH * 2;
    const size_t need     = off_vtz + (size_t)SEQ * NH * DH * 2;

    if (ws_size >= need) {
        int*      flag = (int*)d_ws;
        uint64_t* bits = (uint64_t*)((char*)d_ws + off_bits);
        ushort*   Qb   = (ushort*)((char*)d_ws + off_qb);
        ushort*   Kbz  = (ushort*)((char*)d_ws + off_kbz);
        ushort*   Vtz  = (ushort*)((char*)d_ws + off_vtz);
        detect_kernel<<<1, 256, 0, stream>>>((const uint32_t*)mask, flag);
        pack_kernel<<<SEQ * SEQ / 256, 256, 0, stream>>>(mask, flag, bits);
        convert_q<<<SEQ * NH * DH / (256 * 8), 256, 0, stream>>>(Q, Qb);
        convert_kv<<<dim3(NKT, NH), 256, 0, stream>>>(K, V, Kbz, Vtz);
        attn4<<<NQB * NH, 256, 0, stream>>>(Qb, Kbz, Vtz, bits, out);
    } else {
        attn_fb<<<dim3(NKT, NH), 256, 0, stream>>>(Q, K, V, (const int*)mask, out);
    }
}